// Round 22
// baseline (303.296 us; speedup 1.0000x reference)
//
#include <hip/hip_runtime.h>

typedef unsigned short u16;
typedef __bf16 bf16x8 __attribute__((ext_vector_type(8)));
typedef float f32x4 __attribute__((ext_vector_type(4)));
typedef u16 u16x8 __attribute__((ext_vector_type(8)));

constexpr int T_DIM = 4096;
constexpr int DH    = 256;

__device__ __forceinline__ u16 f2bf(float f) {
    union { float f; unsigned u; } v; v.f = f;
    return (u16)((v.u + 0x7FFFu + ((v.u >> 16) & 1u)) >> 16);
}

// async global->LDS, 16B per lane; LDS dest = wave-uniform base + lane*16
__device__ __forceinline__ void gload_lds(const void* g, void* l) {
    __builtin_amdgcn_global_load_lds(
        (const __attribute__((address_space(1))) void*)g,
        (__attribute__((address_space(3))) void*)l, 16, 0, 0);
}

// ---------------- prep: Wt[j][k] = bf16(W[k][j]) ----------------
__global__ __launch_bounds__(256) void prep_w(
    const float* __restrict__ Wq, const float* __restrict__ Wk,
    const float* __restrict__ Wv, const float* __restrict__ Wo,
    u16* __restrict__ Wqt, u16* __restrict__ Wkt,
    u16* __restrict__ Wvt, u16* __restrict__ Wot)
{
    int idx = blockIdx.x * 256 + threadIdx.x;
    int j = idx >> 8, k = idx & 255;
    int s = k * 256 + j;
    Wqt[idx] = f2bf(Wq[s]);
    Wkt[idx] = f2bf(Wk[s]);
    Wvt[idx] = f2bf(Wv[s]);
    Wot[idx] = f2bf(Wo[s]);
}

// ---------------- QKV projection v2: 128 rows/block, 8 waves, W via LDS dbuf ----------------
__global__ __launch_bounds__(512, 2) void qkv_kernel(
    const float* __restrict__ x,
    const u16* __restrict__ Wqt, const u16* __restrict__ Wkt, const u16* __restrict__ Wvt,
    const float* __restrict__ bq, const float* __restrict__ bk, const float* __restrict__ bv,
    u16* __restrict__ Qg, u16* __restrict__ Kg, u16* __restrict__ Vtg)
{
    __shared__ __align__(16) char lds[131072];   // xl 64KB (reused for V^T) | W dbuf 2x32KB
    char* xl = lds;
    const int tid = threadIdx.x;
    const int w = tid >> 6, l = tid & 63;
    const int lr = l & 15, lh = l >> 4;
    const long row0 = (long)blockIdx.x * 128;
    const long bb   = row0 >> 12;                 // batch (blocks never straddle)
    const int  t0   = (int)(row0 & 4095);

    const u16*  Wt3[3] = { Wqt, Wkt, Wvt };
    const float* b3[3] = { bq, bk, bv };

    // stage W quarter 0 (tgt 0, qtr 0) into buf0 first (longest latency)
    {
        char* wb = lds + 65536;
        const char* ws = (const char*)Wqt;
        #pragma unroll
        for (int i = 0; i < 4; ++i) {
            int off = tid * 16 + i * 8192;
            int roww = off >> 9, slot = (off >> 4) & 31;
            gload_lds(ws + roww * 512 + ((slot * 16) ^ ((roww & 7) << 4)), wb + off);
        }
    }
    // stage x tile [128][256] f32 -> bf16, swizzled
    #pragma unroll
    for (int i = 0; i < 8; ++i) {
        int sid = tid + i * 512;
        int row = sid >> 5, slot = sid & 31;
        const float* src = x + (row0 + row) * DH + slot * 8;
        float4 a  = *(const float4*)(src);
        float4 b2 = *(const float4*)(src + 4);
        u16x8 p;
        p[0] = f2bf(a.x);  p[1] = f2bf(a.y);  p[2] = f2bf(a.z);  p[3] = f2bf(a.w);
        p[4] = f2bf(b2.x); p[5] = f2bf(b2.y); p[6] = f2bf(b2.z); p[7] = f2bf(b2.w);
        *(u16x8*)(xl + row * 512 + ((slot * 16) ^ ((row & 7) << 4))) = p;
    }
    __syncthreads();

    // A-frags for the wave's 16 rows; xl is DEAD afterwards (reused as V^T buffer)
    bf16x8 af[8];
    const int arow = w * 16 + lr;
    #pragma unroll
    for (int ks = 0; ks < 8; ++ks)
        af[ks] = *(const bf16x8*)(xl + arow * 512 + ((ks * 64 + lh * 16) ^ ((arow & 7) << 4)));

    // 12 phases: tgt = p>>2 (Q,K,V), qtr = p&3 (64 output cols each), W dbuf
    for (int p = 0; p < 12; ++p) {
        char* wb = lds + 65536 + (p & 1) * 32768;
        if (p < 11) {
            int pn = p + 1;
            const char* ws = (const char*)Wt3[pn >> 2] + (pn & 3) * 32768;
            char* wn = lds + 65536 + (pn & 1) * 32768;
            #pragma unroll
            for (int i = 0; i < 4; ++i) {
                int off = tid * 16 + i * 8192;
                int roww = off >> 9, slot = (off >> 4) & 31;
                gload_lds(ws + roww * 512 + ((slot * 16) ^ ((roww & 7) << 4)), wn + off);
            }
        }
        const int tgt = p >> 2, qtr = p & 3;
        f32x4 acc[4] = {};
        #pragma unroll
        for (int ks = 0; ks < 8; ++ks) {
            #pragma unroll
            for (int n = 0; n < 4; ++n) {
                int nl = n * 16 + lr;
                bf16x8 bf = *(const bf16x8*)(wb + nl * 512 + ((ks * 64 + lh * 16) ^ ((nl & 7) << 4)));
                acc[n] = __builtin_amdgcn_mfma_f32_16x16x32_bf16(af[ks], bf, acc[n], 0, 0, 0);
            }
        }
        const float* bias = b3[tgt];
        if (tgt < 2) {
            u16* dst = (tgt == 0) ? Qg : Kg;
            long grow = row0 + w * 16 + lh * 4;
            #pragma unroll
            for (int n = 0; n < 4; ++n) {
                int col = qtr * 64 + n * 16 + lr;
                float bbv = bias[col];
                #pragma unroll
                for (int r = 0; r < 4; ++r)
                    dst[(grow + r) * DH + col] = f2bf(acc[n][r] + bbv);
            }
        } else {
            // V: write transposed into xl [256 d][128 t] bf16, swizzled
            #pragma unroll
            for (int n = 0; n < 4; ++n) {
                int d = qtr * 64 + n * 16 + lr;
                float bbv = bias[d];
                #pragma unroll
                for (int r = 0; r < 4; ++r) {
                    int t = w * 16 + lh * 4 + r;
                    *(u16*)(xl + d * 256 + ((t * 2) ^ ((d & 7) << 4))) = f2bf(acc[n][r] + bbv);
                }
            }
        }
        __syncthreads();   // wb consumed; stage for p+1 drained
    }

    // coalesced V^T copy-out
    #pragma unroll
    for (int i = 0; i < 8; ++i) {
        int sid = tid + i * 512;
        int d = sid >> 4, slot = sid & 15;
        u16x8 v = *(const u16x8*)(xl + d * 256 + ((slot * 16) ^ ((d & 7) << 4)));
        *(u16x8*)((char*)Vtg + ((bb * DH + d) * T_DIM + t0) * 2 + slot * 16) = v;
    }
}

// ---- fused retention + out-proj: ONE barrier/iter, wave-private P ----
// Each wave computes QK^T for its 32 q-rows over the FULL 64 s-cols (QK^T is
// duplicated across the dh pair, +50% QK^T MFMAs), gates, and writes P to a
// PRIVATE 4KB slab. The PV A-frag read then touches only this wave's own
// writes -> intra-wave lgkmcnt ordering suffices, NO mid-iter barrier.
// LDS = K/V dbuf 128KB + P 32KB = 160KB (1 WG/CU; 256-VGPR allocator budget).
__global__ __launch_bounds__(512, 2) void retention_kernel(
    const u16* __restrict__ Qg, const u16* __restrict__ Kg, const u16* __restrict__ Vtg,
    const float* __restrict__ gamma, const u16* __restrict__ Wot,
    const float* __restrict__ bo, const float* __restrict__ pa,
    float* __restrict__ out)
{
    __shared__ __align__(16) char base[163840];   // K/V dbuf 128KB | P 8x4KB private
    const int tid = threadIdx.x;
    const int w = tid >> 6, l = tid & 63;
    const int lr = l & 15, lh = l >> 4;
    const int wq = w >> 1, dh = w & 1;            // q-chunk (32 rows), d-half (128 cols)
    const int b  = blockIdx.x >> 5;
    const int q0 = (blockIdx.x & 31) * 128;

    char* pb = base + 131072 + w * 4096;          // this wave's PRIVATE P [32 q][64 s]
    const char* kgb = (const char*)(Kg + (long)b * T_DIM * DH);
    const char* vgb = (const char*)Vtg + (long)b * DH * T_DIM * 2;
    const float* gwave = gamma + (long)(q0 + wq * 32) * T_DIM;

    // Q A-frags (persistent 64 VGPRs)
    bf16x8 qf[2][8];
    #pragma unroll
    for (int rg = 0; rg < 2; ++rg) {
        const char* qb = (const char*)(Qg + ((long)b * T_DIM + q0 + wq * 32 + rg * 16 + lr) * DH);
        #pragma unroll
        for (int ks = 0; ks < 8; ++ks)
            qf[rg][ks] = *(const bf16x8*)(qb + ks * 64 + lh * 16);
    }

    f32x4 acc[2][8] = {};                         // 32 rows x 128 cols -> 64 VGPRs

    // prologue: stage tile 0 into buf0
    {
        char* kn = base;
        #pragma unroll
        for (int i = 0; i < 4; ++i) {
            int off = w * 4096 + i * 1024 + l * 16;
            int row = off >> 9, slot = (off >> 4) & 31;
            gload_lds(kgb + row * 512 + ((slot * 16) ^ ((row & 7) << 4)),
                      kn + w * 4096 + i * 1024);
        }
        char* vn = base + 32768;
        #pragma unroll
        for (int i = 0; i < 4; ++i) {
            int off = w * 4096 + i * 1024 + l * 16;
            int row = off >> 7, slot = (off >> 4) & 7;
            gload_lds(vgb + (long)row * (T_DIM * 2) + ((slot * 16) ^ ((row & 7) << 4)),
                      vn + w * 4096 + i * 1024);
        }
    }
    __syncthreads();

    for (int it = 0; it < 64; ++it) {
        const int s0 = it * 64;
        char* kl = base + (it & 1) * 65536;
        char* vl = kl + 32768;

        // 1. gamma for THIS iter (full 64 s-cols for our 32 q-rows) — issued FIRST
        //    so its wait never retires the newer staging gloads (vmcnt FIFO).
        float gv[2][4][4];
        {
            const float* gp = gwave + s0;
            #pragma unroll
            for (int rg = 0; rg < 2; ++rg)
                #pragma unroll
                for (int n = 0; n < 4; ++n)
                    #pragma unroll
                    for (int r = 0; r < 4; ++r)
                        gv[rg][n][r] = gp[(long)(rg * 16 + lh * 4 + r) * T_DIM + n * 16 + lr];
        }
        __builtin_amdgcn_sched_barrier(0);

        // 2. issue next tile's loads into the other buffer (stay in flight all iter)
        if (it < 63) {
            const char* kg = kgb + (long)(s0 + 64) * 512;
            char* kn = base + ((it + 1) & 1) * 65536;
            #pragma unroll
            for (int i = 0; i < 4; ++i) {
                int off = w * 4096 + i * 1024 + l * 16;
                int row = off >> 9, slot = (off >> 4) & 31;
                gload_lds(kg + row * 512 + ((slot * 16) ^ ((row & 7) << 4)),
                          kn + w * 4096 + i * 1024);
            }
            const char* vg = vgb + (long)(s0 + 64) * 2;
            char* vn = kn + 32768;
            #pragma unroll
            for (int i = 0; i < 4; ++i) {
                int off = w * 4096 + i * 1024 + l * 16;
                int row = off >> 7, slot = (off >> 4) & 7;
                gload_lds(vg + (long)row * (T_DIM * 2) + ((slot * 16) ^ ((row & 7) << 4)),
                          vn + w * 4096 + i * 1024);
            }
        }

        // 3. QK^T: 32 q-rows x FULL 64 s-cols, gate, pack bf16, write PRIVATE P
        #pragma unroll
        for (int n = 0; n < 4; ++n) {
            f32x4 sa = {}, sb = {};
            const int srow = n * 16 + lr;
            #pragma unroll
            for (int ks = 0; ks < 8; ++ks) {
                bf16x8 kf = *(const bf16x8*)(kl + srow * 512 + ((ks * 64 + lh * 16) ^ ((srow & 7) << 4)));
                sa = __builtin_amdgcn_mfma_f32_16x16x32_bf16(qf[0][ks], kf, sa, 0, 0, 0);
                sb = __builtin_amdgcn_mfma_f32_16x16x32_bf16(qf[1][ks], kf, sb, 0, 0, 0);
            }
            const int cb = (n * 16 + lr) * 2;
            #pragma unroll
            for (int r = 0; r < 4; ++r) {
                int pr0 = lh * 4 + r;              // q-local row, rg=0
                int pr1 = pr0 + 16;                // rg=1
                *(u16*)(pb + pr0 * 128 + (cb ^ ((pr0 & 7) << 4))) = f2bf(gv[0][n][r] * sa[r]);
                *(u16*)(pb + pr1 * 128 + (cb ^ ((pr1 & 7) << 4))) = f2bf(gv[1][n][r] * sb[r]);
            }
        }
        // NO barrier: P is wave-private (reads below touch only our own writes;
        // same-wave ds ordering via compiler-inserted lgkmcnt).

        // 4. PV: A = private P rows, B = Vt rows (own 128 d-cols)
        bf16x8 pa2[2][2];
        #pragma unroll
        for (int rg = 0; rg < 2; ++rg)
            #pragma unroll
            for (int k2 = 0; k2 < 2; ++k2) {
                int prr = rg * 16 + lr;
                pa2[rg][k2] = *(const bf16x8*)(pb + prr * 128 + ((k2 * 64 + lh * 16) ^ ((prr & 7) << 4)));
            }
        #pragma unroll
        for (int n = 0; n < 8; ++n) {
            int vrow = dh * 128 + n * 16 + lr;
            #pragma unroll
            for (int k2 = 0; k2 < 2; ++k2) {
                bf16x8 bv = *(const bf16x8*)(vl + vrow * 128 + ((k2 * 64 + lh * 16) ^ ((vrow & 7) << 4)));
                acc[0][n] = __builtin_amdgcn_mfma_f32_16x16x32_bf16(pa2[0][k2], bv, acc[0][n], 0, 0, 0);
                acc[1][n] = __builtin_amdgcn_mfma_f32_16x16x32_bf16(pa2[1][k2], bv, acc[1][n], 0, 0, 0);
            }
        }
        __syncthreads();   // the ONE barrier per iter: next tile ready, K/V reads done
    }

    // ---- fused epilogue: R-tile -> LDS base[0,64K), then out-proj + PReLU ----
    {   // write R [128 q][256 d] bf16, (q&7)<<4 swizzle (proven xlds template)
        #pragma unroll
        for (int rg = 0; rg < 2; ++rg)
            #pragma unroll
            for (int n = 0; n < 8; ++n) {
                int d2 = (dh * 128 + n * 16 + lr) * 2;
                #pragma unroll
                for (int r = 0; r < 4; ++r) {
                    int q = wq * 32 + rg * 16 + lh * 4 + r;
                    *(u16*)(base + q * 512 + (d2 ^ ((q & 7) << 4))) = f2bf(acc[rg][n][r]);
                }
            }
    }
    __syncthreads();
    {   // out = PReLU(R @ Wo + bo): 8 waves x 16 rows
        const int arow = w * 16 + lr;
        f32x4 acc2[16] = {};
        #pragma unroll
        for (int ks = 0; ks < 8; ++ks) {
            bf16x8 a = *(const bf16x8*)(base + arow * 512 +
                        ((ks * 64 + lh * 16) ^ ((arow & 7) << 4)));
            #pragma unroll
            for (int n = 0; n < 16; ++n) {
                bf16x8 bf = *(const bf16x8*)(Wot + (n * 16 + lr) * DH + ks * 32 + lh * 8);
                acc2[n] = __builtin_amdgcn_mfma_f32_16x16x32_bf16(a, bf, acc2[n], 0, 0, 0);
            }
        }
        const float alpha = pa[0];
        long grow = (long)b * T_DIM + q0 + w * 16 + lh * 4;
        #pragma unroll
        for (int n = 0; n < 16; ++n) {
            int col = n * 16 + lr;
            float bb = bo[col];
            #pragma unroll
            for (int r = 0; r < 4; ++r) {
                float y = acc2[n][r] + bb;
                out[(grow + r) * DH + col] = (y >= 0.f) ? y : alpha * y;
            }
        }
    }
}

extern "C" void kernel_launch(void* const* d_in, const int* in_sizes, int n_in,
                              void* d_out, int out_size, void* d_ws, size_t ws_size,
                              hipStream_t stream)
{
    const float* x     = (const float*)d_in[0];
    const float* gamma = (const float*)d_in[1];
    const float* Wq = (const float*)d_in[2];
    const float* bq = (const float*)d_in[3];
    const float* Wk = (const float*)d_in[4];
    const float* bk = (const float*)d_in[5];
    const float* Wv = (const float*)d_in[6];
    const float* bv = (const float*)d_in[7];
    const float* Wo = (const float*)d_in[8];
    const float* bo = (const float*)d_in[9];
    const float* pa = (const float*)d_in[10];
    float* out = (float*)d_out;

    char* ws = (char*)d_ws;
    const long SZ = 16777216L;                 // 8*4096*256 bf16 bytes
    u16* Wqt = (u16*)(ws);
    u16* Wkt = (u16*)(ws + 131072);
    u16* Wvt = (u16*)(ws + 262144);
    u16* Wot = (u16*)(ws + 393216);
    u16* Qg  = (u16*)(ws + 524288);
    u16* Kg  = (u16*)(ws + 524288 + SZ);
    u16* Vtg = (u16*)(ws + 524288 + 2 * SZ);

    hipLaunchKernelGGL(prep_w, dim3(256), dim3(256), 0, stream,
                       Wq, Wk, Wv, Wo, Wqt, Wkt, Wvt, Wot);
    hipLaunchKernelGGL(qkv_kernel, dim3(256), dim3(512), 0, stream,
                       x, Wqt, Wkt, Wvt, bq, bk, bv, Qg, Kg, Vtg);
    hipLaunchKernelGGL(retention_kernel, dim3(256), dim3(512), 0, stream,
                       Qg, Kg, Vtg, gamma, Wot, bo, pa, out);
}

// Round 23
// 225.831 us; speedup vs baseline: 1.3430x; 1.3430x over previous
//
#include <hip/hip_runtime.h>

typedef unsigned short u16;
typedef __bf16 bf16x8 __attribute__((ext_vector_type(8)));
typedef float f32x4 __attribute__((ext_vector_type(4)));
typedef u16 u16x8 __attribute__((ext_vector_type(8)));

constexpr int T_DIM = 4096;
constexpr int DH    = 256;

__device__ __forceinline__ u16 f2bf(float f) {
    union { float f; unsigned u; } v; v.f = f;
    return (u16)((v.u + 0x7FFFu + ((v.u >> 16) & 1u)) >> 16);
}

// async global->LDS, 16B per lane; LDS dest = wave-uniform base + lane*16
__device__ __forceinline__ void gload_lds(const void* g, void* l) {
    __builtin_amdgcn_global_load_lds(
        (const __attribute__((address_space(1))) void*)g,
        (__attribute__((address_space(3))) void*)l, 16, 0, 0);
}

// ---------------- prep: Wt[j][k] = bf16(W[k][j]) ----------------
__global__ __launch_bounds__(256) void prep_w(
    const float* __restrict__ Wq, const float* __restrict__ Wk,
    const float* __restrict__ Wv, const float* __restrict__ Wo,
    u16* __restrict__ Wqt, u16* __restrict__ Wkt,
    u16* __restrict__ Wvt, u16* __restrict__ Wot)
{
    int idx = blockIdx.x * 256 + threadIdx.x;
    int j = idx >> 8, k = idx & 255;
    int s = k * 256 + j;
    Wqt[idx] = f2bf(Wq[s]);
    Wkt[idx] = f2bf(Wk[s]);
    Wvt[idx] = f2bf(Wv[s]);
    Wot[idx] = f2bf(Wo[s]);
}

// ---------------- QKV projection v2: 128 rows/block, 8 waves, W via LDS dbuf ----------------
__global__ __launch_bounds__(512, 2) void qkv_kernel(
    const float* __restrict__ x,
    const u16* __restrict__ Wqt, const u16* __restrict__ Wkt, const u16* __restrict__ Wvt,
    const float* __restrict__ bq, const float* __restrict__ bk, const float* __restrict__ bv,
    u16* __restrict__ Qg, u16* __restrict__ Kg, u16* __restrict__ Vtg)
{
    __shared__ __align__(16) char lds[131072];   // xl 64KB (reused for V^T) | W dbuf 2x32KB
    char* xl = lds;
    const int tid = threadIdx.x;
    const int w = tid >> 6, l = tid & 63;
    const int lr = l & 15, lh = l >> 4;
    const long row0 = (long)blockIdx.x * 128;
    const long bb   = row0 >> 12;                 // batch (blocks never straddle)
    const int  t0   = (int)(row0 & 4095);

    const u16*  Wt3[3] = { Wqt, Wkt, Wvt };
    const float* b3[3] = { bq, bk, bv };

    // stage W quarter 0 (tgt 0, qtr 0) into buf0 first (longest latency)
    {
        char* wb = lds + 65536;
        const char* ws = (const char*)Wqt;
        #pragma unroll
        for (int i = 0; i < 4; ++i) {
            int off = tid * 16 + i * 8192;
            int roww = off >> 9, slot = (off >> 4) & 31;
            gload_lds(ws + roww * 512 + ((slot * 16) ^ ((roww & 7) << 4)), wb + off);
        }
    }
    // stage x tile [128][256] f32 -> bf16, swizzled
    #pragma unroll
    for (int i = 0; i < 8; ++i) {
        int sid = tid + i * 512;
        int row = sid >> 5, slot = sid & 31;
        const float* src = x + (row0 + row) * DH + slot * 8;
        float4 a  = *(const float4*)(src);
        float4 b2 = *(const float4*)(src + 4);
        u16x8 p;
        p[0] = f2bf(a.x);  p[1] = f2bf(a.y);  p[2] = f2bf(a.z);  p[3] = f2bf(a.w);
        p[4] = f2bf(b2.x); p[5] = f2bf(b2.y); p[6] = f2bf(b2.z); p[7] = f2bf(b2.w);
        *(u16x8*)(xl + row * 512 + ((slot * 16) ^ ((row & 7) << 4))) = p;
    }
    __syncthreads();

    // A-frags for the wave's 16 rows; xl is DEAD afterwards (reused as V^T buffer)
    bf16x8 af[8];
    const int arow = w * 16 + lr;
    #pragma unroll
    for (int ks = 0; ks < 8; ++ks)
        af[ks] = *(const bf16x8*)(xl + arow * 512 + ((ks * 64 + lh * 16) ^ ((arow & 7) << 4)));

    // 12 phases: tgt = p>>2 (Q,K,V), qtr = p&3 (64 output cols each), W dbuf
    for (int p = 0; p < 12; ++p) {
        char* wb = lds + 65536 + (p & 1) * 32768;
        if (p < 11) {
            int pn = p + 1;
            const char* ws = (const char*)Wt3[pn >> 2] + (pn & 3) * 32768;
            char* wn = lds + 65536 + (pn & 1) * 32768;
            #pragma unroll
            for (int i = 0; i < 4; ++i) {
                int off = tid * 16 + i * 8192;
                int roww = off >> 9, slot = (off >> 4) & 31;
                gload_lds(ws + roww * 512 + ((slot * 16) ^ ((roww & 7) << 4)), wn + off);
            }
        }
        const int tgt = p >> 2, qtr = p & 3;
        f32x4 acc[4] = {};
        #pragma unroll
        for (int ks = 0; ks < 8; ++ks) {
            #pragma unroll
            for (int n = 0; n < 4; ++n) {
                int nl = n * 16 + lr;
                bf16x8 bf = *(const bf16x8*)(wb + nl * 512 + ((ks * 64 + lh * 16) ^ ((nl & 7) << 4)));
                acc[n] = __builtin_amdgcn_mfma_f32_16x16x32_bf16(af[ks], bf, acc[n], 0, 0, 0);
            }
        }
        const float* bias = b3[tgt];
        if (tgt < 2) {
            u16* dst = (tgt == 0) ? Qg : Kg;
            long grow = row0 + w * 16 + lh * 4;
            #pragma unroll
            for (int n = 0; n < 4; ++n) {
                int col = qtr * 64 + n * 16 + lr;
                float bbv = bias[col];
                #pragma unroll
                for (int r = 0; r < 4; ++r)
                    dst[(grow + r) * DH + col] = f2bf(acc[n][r] + bbv);
            }
        } else {
            // V: write transposed into xl [256 d][128 t] bf16, swizzled
            #pragma unroll
            for (int n = 0; n < 4; ++n) {
                int d = qtr * 64 + n * 16 + lr;
                float bbv = bias[d];
                #pragma unroll
                for (int r = 0; r < 4; ++r) {
                    int t = w * 16 + lh * 4 + r;
                    *(u16*)(xl + d * 256 + ((t * 2) ^ ((d & 7) << 4))) = f2bf(acc[n][r] + bbv);
                }
            }
        }
        __syncthreads();   // wb consumed; stage for p+1 drained
    }

    // coalesced V^T copy-out
    #pragma unroll
    for (int i = 0; i < 8; ++i) {
        int sid = tid + i * 512;
        int d = sid >> 4, slot = sid & 15;
        u16x8 v = *(const u16x8*)(xl + d * 256 + ((slot * 16) ^ ((d & 7) << 4)));
        *(u16x8*)((char*)Vtg + ((bb * DH + d) * T_DIM + t0) * 2 + slot * 16) = v;
    }
}

// ---- fused retention + out-proj: best-measured configuration (R9/R16/R21, 226 us) ----
// Manual f2bf pack + (row&7)<<4 swizzle on BOTH P write and read; mid-iter barrier
// LDS-only (no vmcnt drain); one full drain per iter at the end __syncthreads.
__global__ __launch_bounds__(512, 2) void retention_kernel(
    const u16* __restrict__ Qg, const u16* __restrict__ Kg, const u16* __restrict__ Vtg,
    const float* __restrict__ gamma, const u16* __restrict__ Wot,
    const float* __restrict__ bo, const float* __restrict__ pa,
    float* __restrict__ out)
{
    __shared__ __align__(16) char base[147456];   // K/V dbuf 128KB | P 16KB; R-tile reuses [0,64K)
    char* pl = base + 131072;
    const int tid = threadIdx.x;
    const int w = tid >> 6, l = tid & 63;
    const int lr = l & 15, lh = l >> 4;
    const int wq = w >> 1, dh = w & 1;            // q-chunk (32 rows), d-half (128 cols)
    const int b  = blockIdx.x >> 5;
    const int q0 = (blockIdx.x & 31) * 128;

    const char* kgb = (const char*)(Kg + (long)b * T_DIM * DH);
    const char* vgb = (const char*)Vtg + (long)b * DH * T_DIM * 2;
    const float* gwave = gamma + (long)(q0 + wq * 32) * T_DIM + dh * 32;

    // Q A-frags (persistent 64 VGPRs)
    bf16x8 qf[2][8];
    #pragma unroll
    for (int rg = 0; rg < 2; ++rg) {
        const char* qb = (const char*)(Qg + ((long)b * T_DIM + q0 + wq * 32 + rg * 16 + lr) * DH);
        #pragma unroll
        for (int ks = 0; ks < 8; ++ks)
            qf[rg][ks] = *(const bf16x8*)(qb + ks * 64 + lh * 16);
    }

    f32x4 acc[2][8] = {};                         // 32 rows x 128 cols -> 64 VGPRs

    // prologue: stage tile 0 into buf0
    {
        char* kn = base;
        #pragma unroll
        for (int i = 0; i < 4; ++i) {
            int off = w * 4096 + i * 1024 + l * 16;
            int row = off >> 9, slot = (off >> 4) & 31;
            gload_lds(kgb + row * 512 + ((slot * 16) ^ ((row & 7) << 4)),
                      kn + w * 4096 + i * 1024);
        }
        char* vn = base + 32768;
        #pragma unroll
        for (int i = 0; i < 4; ++i) {
            int off = w * 4096 + i * 1024 + l * 16;
            int row = off >> 7, slot = (off >> 4) & 7;
            gload_lds(vgb + (long)row * (T_DIM * 2) + ((slot * 16) ^ ((row & 7) << 4)),
                      vn + w * 4096 + i * 1024);
        }
    }
    __syncthreads();

    for (int it = 0; it < 64; ++it) {
        const int s0 = it * 64;
        char* kl = base + (it & 1) * 65536;
        char* vl = kl + 32768;

        // 1. gamma for THIS iter — issued FIRST so its wait never retires the
        //    newer staging gloads (vmcnt FIFO).
        float gv0[2][4], gv1[2][4];
        {
            const float* gp = gwave + s0;
            #pragma unroll
            for (int n = 0; n < 2; ++n)
                #pragma unroll
                for (int r = 0; r < 4; ++r) {
                    gv0[n][r] = gp[(long)(lh * 4 + r) * T_DIM + n * 16 + lr];
                    gv1[n][r] = gp[(long)(16 + lh * 4 + r) * T_DIM + n * 16 + lr];
                }
        }
        __builtin_amdgcn_sched_barrier(0);

        // 2. issue next tile's loads into the other buffer (stay in flight all iter)
        if (it < 63) {
            const char* kg = kgb + (long)(s0 + 64) * 512;
            char* kn = base + ((it + 1) & 1) * 65536;
            #pragma unroll
            for (int i = 0; i < 4; ++i) {
                int off = w * 4096 + i * 1024 + l * 16;
                int row = off >> 9, slot = (off >> 4) & 31;
                gload_lds(kg + row * 512 + ((slot * 16) ^ ((row & 7) << 4)),
                          kn + w * 4096 + i * 1024);
            }
            const char* vg = vgb + (long)(s0 + 64) * 2;
            char* vn = kn + 32768;
            #pragma unroll
            for (int i = 0; i < 4; ++i) {
                int off = w * 4096 + i * 1024 + l * 16;
                int row = off >> 7, slot = (off >> 4) & 7;
                gload_lds(vg + (long)row * (T_DIM * 2) + ((slot * 16) ^ ((row & 7) << 4)),
                          vn + w * 4096 + i * 1024);
            }
        }

        // 3. QK^T (32 q x 32 s, own dh half), gate, pack bf16 (f2bf), write P
        //    with the proven (pr&7)<<4 swizzle
        #pragma unroll
        for (int n = 0; n < 2; ++n) {
            f32x4 sa = {}, sb = {};
            const int srow = dh * 32 + n * 16 + lr;
            #pragma unroll
            for (int ks = 0; ks < 8; ++ks) {
                bf16x8 kf = *(const bf16x8*)(kl + srow * 512 + ((ks * 64 + lh * 16) ^ ((srow & 7) << 4)));
                sa = __builtin_amdgcn_mfma_f32_16x16x32_bf16(qf[0][ks], kf, sa, 0, 0, 0);
                sb = __builtin_amdgcn_mfma_f32_16x16x32_bf16(qf[1][ks], kf, sb, 0, 0, 0);
            }
            const int cb = (dh * 32 + n * 16 + lr) * 2;
            #pragma unroll
            for (int r = 0; r < 4; ++r) {
                int pr0 = wq * 32 + lh * 4 + r;
                int pr1 = pr0 + 16;
                *(u16*)(pl + pr0 * 128 + (cb ^ ((pr0 & 7) << 4))) = f2bf(gv0[n][r] * sa[r]);
                *(u16*)(pl + pr1 * 128 + (cb ^ ((pr1 & 7) << 4))) = f2bf(gv1[n][r] * sb[r]);
            }
        }

        // 4. mid-iter barrier: LDS-only (dh-partner reads my P s-cols); vmcnt untouched.
        __builtin_amdgcn_sched_barrier(0);
        asm volatile("s_waitcnt lgkmcnt(0)" ::: "memory");
        __builtin_amdgcn_s_barrier();
        __builtin_amdgcn_sched_barrier(0);

        // 5. PV: A = P rows (own 32, full 64 s-cols), B = Vt rows (own 128 d-cols)
        bf16x8 pa2[2][2];
        #pragma unroll
        for (int rg = 0; rg < 2; ++rg)
            #pragma unroll
            for (int k2 = 0; k2 < 2; ++k2) {
                int prr = wq * 32 + rg * 16 + lr;
                pa2[rg][k2] = *(const bf16x8*)(pl + prr * 128 + ((k2 * 64 + lh * 16) ^ ((prr & 7) << 4)));
            }
        #pragma unroll
        for (int n = 0; n < 8; ++n) {
            int vrow = dh * 128 + n * 16 + lr;
            #pragma unroll
            for (int k2 = 0; k2 < 2; ++k2) {
                bf16x8 bv = *(const bf16x8*)(vl + vrow * 128 + ((k2 * 64 + lh * 16) ^ ((vrow & 7) << 4)));
                acc[0][n] = __builtin_amdgcn_mfma_f32_16x16x32_bf16(pa2[0][k2], bv, acc[0][n], 0, 0, 0);
                acc[1][n] = __builtin_amdgcn_mfma_f32_16x16x32_bf16(pa2[1][k2], bv, acc[1][n], 0, 0, 0);
            }
        }
        __syncthreads();   // the ONE full drain per iter: next tile ready, P reads done
    }

    // ---- fused epilogue: R-tile -> LDS base[0,64K), then out-proj + PReLU ----
    {   // write R [128 q][256 d] bf16, (q&7)<<4 swizzle (proven xlds template)
        #pragma unroll
        for (int rg = 0; rg < 2; ++rg)
            #pragma unroll
            for (int n = 0; n < 8; ++n) {
                int d2 = (dh * 128 + n * 16 + lr) * 2;
                #pragma unroll
                for (int r = 0; r < 4; ++r) {
                    int q = wq * 32 + rg * 16 + lh * 4 + r;
                    *(u16*)(base + q * 512 + (d2 ^ ((q & 7) << 4))) = f2bf(acc[rg][n][r]);
                }
            }
    }
    __syncthreads();
    {   // out = PReLU(R @ Wo + bo): 8 waves x 16 rows
        const int arow = w * 16 + lr;
        f32x4 acc2[16] = {};
        #pragma unroll
        for (int ks = 0; ks < 8; ++ks) {
            bf16x8 a = *(const bf16x8*)(base + arow * 512 +
                        ((ks * 64 + lh * 16) ^ ((arow & 7) << 4)));
            #pragma unroll
            for (int n = 0; n < 16; ++n) {
                bf16x8 bf = *(const bf16x8*)(Wot + (n * 16 + lr) * DH + ks * 32 + lh * 8);
                acc2[n] = __builtin_amdgcn_mfma_f32_16x16x32_bf16(a, bf, acc2[n], 0, 0, 0);
            }
        }
        const float alpha = pa[0];
        long grow = (long)b * T_DIM + q0 + w * 16 + lh * 4;
        #pragma unroll
        for (int n = 0; n < 16; ++n) {
            int col = n * 16 + lr;
            float bb = bo[col];
            #pragma unroll
            for (int r = 0; r < 4; ++r) {
                float y = acc2[n][r] + bb;
                out[(grow + r) * DH + col] = (y >= 0.f) ? y : alpha * y;
            }
        }
    }
}

extern "C" void kernel_launch(void* const* d_in, const int* in_sizes, int n_in,
                              void* d_out, int out_size, void* d_ws, size_t ws_size,
                              hipStream_t stream)
{
    const float* x     = (const float*)d_in[0];
    const float* gamma = (const float*)d_in[1];
    const float* Wq = (const float*)d_in[2];
    const float* bq = (const float*)d_in[3];
    const float* Wk = (const float*)d_in[4];
    const float* bk = (const float*)d_in[5];
    const float* Wv = (const float*)d_in[6];
    const float* bv = (const float*)d_in[7];
    const float* Wo = (const float*)d_in[8];
    const float* bo = (const float*)d_in[9];
    const float* pa = (const float*)d_in[10];
    float* out = (float*)d_out;

    char* ws = (char*)d_ws;
    const long SZ = 16777216L;                 // 8*4096*256 bf16 bytes
    u16* Wqt = (u16*)(ws);
    u16* Wkt = (u16*)(ws + 131072);
    u16* Wvt = (u16*)(ws + 262144);
    u16* Wot = (u16*)(ws + 393216);
    u16* Qg  = (u16*)(ws + 524288);
    u16* Kg  = (u16*)(ws + 524288 + SZ);
    u16* Vtg = (u16*)(ws + 524288 + 2 * SZ);

    hipLaunchKernelGGL(prep_w, dim3(256), dim3(256), 0, stream,
                       Wq, Wk, Wv, Wo, Wqt, Wkt, Wvt, Wot);
    hipLaunchKernelGGL(qkv_kernel, dim3(256), dim3(512), 0, stream,
                       x, Wqt, Wkt, Wvt, bq, bk, bv, Qg, Kg, Vtg);
    hipLaunchKernelGGL(retention_kernel, dim3(256), dim3(512), 0, stream,
                       Qg, Kg, Vtg, gamma, Wot, bo, pa, out);
}